// Round 18
// baseline (278.990 us; speedup 1.0000x reference)
//
#include <hip/hip_runtime.h>
#include <math.h>

// SuperVoxel critical-component loss on MI355X.
// mean( (0.5 + 0.25*neg + 0.25*pos) * bce_loss )
// Run-based two-level CCL with path-halving union-find and PER-RUN loss sums.
//  k_mls:   FUSED maskloss+strip. One block per (image, strip): 8 waves x 4
//           rows compute loss/masks/run-sums (round-16 body, mistake bit in
//           runsum SIGN), then the same block runs both phases' intra-strip
//           CCL in 64KB LDS (unions, flag ORs onto static roots, compress).
//           Memory phase of one resident block overlaps CCL of the other.
//  k_bound: global flag-carrying unions on 31 strip seams per image.
//  k_accumrun: per used run slot (x4 vectorized): root flag ? 0.25*|runsum|.

#define HH 1024
#define WW 1024
#define IMGPIX (HH * WW)
#define NB_TOTAL 16
#define FLAGBIT 0x40000000
#define IDXMASK 0x3FFFFFFF
#define NBLK 2048
#define NPART 2048
#define NTHR 256
#define WPR 16               // u64 mask words per row
#define RPR 512              // run slots per row (hard worst case)
#define SROWS 32             // rows per strip
#define STRIPS (HH / SROWS)  // 32 strips per image
#define SLOTS (SROWS * RPR)  // 16384 slots per strip (64KB LDS)
#define NTHR_F 512           // fused kernel block size (8 waves)

typedef unsigned long long u64;

// ---------- global union-find, path-halving, flag-aware ----------
__device__ __forceinline__ int findRootH(int* p, int i) {
    volatile int* vp = p;
    int r = i;
    int e = vp[r] & IDXMASK;
    while (e != r) {
        int e2 = vp[e] & IDXMASK;
        if (e2 != e) p[r] = e2;  // shortcut: only non-roots written (no flags there)
        r = e; e = e2;
    }
    return r;
}

__device__ __forceinline__ void flagProp(int* p, int x) {
    while (true) {
        int r = findRootH(p, x);
        int old = atomicOr(&p[r], FLAGBIT);
        if ((old & IDXMASK) == r) return;  // was still a root
        x = old & IDXMASK;
    }
}

__device__ __forceinline__ void uniteGF(int* p, int a, int b) {
    int ra = findRootH(p, a), rb = findRootH(p, b);
    while (ra != rb) {
        if (ra < rb) { int t = ra; ra = rb; rb = t; }  // hook larger under smaller
        int e = p[ra];
        if ((e & IDXMASK) != ra) { ra = findRootH(p, e & IDXMASK); continue; }
        int prev = atomicCAS(&p[ra], e, rb);
        if (prev == e) {
            if (e & FLAGBIT) flagProp(p, rb);
            return;
        }
        ra = findRootH(p, prev & IDXMASK);
        rb = findRootH(p, rb);
    }
}

// ---------- LDS union-find, path-halving ----------
__device__ __forceinline__ int findRootL(int* lab, int i) {
    volatile int* vl = lab;
    int r = i;
    int e = vl[r] & IDXMASK;
    while (e != r) {
        int e2 = vl[e] & IDXMASK;
        if (e2 != e) lab[r] = e2;
        r = e; e = e2;
    }
    return r;
}

__device__ __forceinline__ void uniteL(int* lab, int a, int b) {
    int ra = findRootL(lab, a), rb = findRootL(lab, b);
    while (ra != rb) {
        if (ra < rb) { int t = ra; ra = rb; rb = t; }
        int prev = atomicCAS(&lab[ra], ra, rb);
        if (prev == ra) return;
        ra = findRootL(lab, prev & IDXMASK);
        rb = findRootL(lab, rb);
    }
}

// index (within row) of the run containing bit b of this word; requires fg@b.
__device__ __forceinline__ int runIndexW(u64 starts, int b) {
    u64 below = (2ULL << b) - 1ULL;  // b=63 wraps to ~0ULL
    return (int)__popcll(starts & below) - 1;
}

__global__ void k_zero(double* __restrict__ part) {
    part[blockIdx.x * blockDim.x + threadIdx.x] = 0.0;
}

__device__ __forceinline__ float packf(float mag, bool fl) {
    return __uint_as_float(__float_as_uint(mag) | (fl ? 0x80000000u : 0u));
}

// Per-phase body (after merged count scan): serial in-lane loop writes
// complete runs; trailing-run resolution is local unless some lane's mask is
// fully set (then the full 6-step segmented scan runs, ballot-guarded).
__device__ __forceinline__ void phaseBody(int lane, int mask, int mist, int starts,
                                          int carry, int excl, int incl,
                                          const float* lossv, long rbase,
                                          float* __restrict__ runsum) {
    float cur = 0.0f, headmag = 0.0f;
    bool curf = false, headf = false;
    bool begun = false, prevfg = (carry != 0), hasHead = false;
    int scount = 0;
    #pragma unroll
    for (int k = 0; k < 16; ++k) {
        bool fg = (mask >> k) & 1;
        bool mk = (mist >> k) & 1;
        if (fg) {
            if ((starts >> k) & 1) { cur = lossv[k]; curf = mk; begun = true; ++scount; }
            else { cur += lossv[k]; curf |= mk; }
        } else {
            if (prevfg) {
                if (begun) runsum[rbase + excl + scount - 1] = packf(cur, curf);
                else { hasHead = true; headmag = cur; headf = curf; }
            }
        }
        prevfg = fg;
    }
    float sv = prevfg ? packf(cur, curf) : 0.0f;
    u64 fullb = __ballot(mask == 0xFFFF);
    if (fullb) {
        int fl = (starts != 0);
        #pragma unroll
        for (int d = 1; d < 64; d <<= 1) {
            float u = __shfl_up(sv, d, 64);
            int uf = __shfl_up(fl, d, 64);
            if (lane >= d) {
                if (!fl) {
                    unsigned sg = (__float_as_uint(sv) | __float_as_uint(u)) & 0x80000000u;
                    float mag = fabsf(sv) + fabsf(u);
                    sv = __uint_as_float(__float_as_uint(mag) | sg);
                }
                fl |= uf;
            }
        }
    }
    float svprev = __shfl_up(sv, 1, 64);
    if (hasHead) {
        unsigned sg = (__float_as_uint(svprev) & 0x80000000u) | (headf ? 0x80000000u : 0u);
        float mag = fabsf(svprev) + headmag;
        runsum[rbase + excl - 1] = __uint_as_float(__float_as_uint(mag) | sg);
    }
    if (lane == 63 && prevfg) runsum[rbase + incl - 1] = sv;  // keeps packed sign
}

// FUSED maskloss + strip CCL. One block per (image, strip).
__global__ __launch_bounds__(NTHR_F) void
k_mls(const float* __restrict__ preds, const float* __restrict__ targets,
      long gbase,
      u64* __restrict__ fT, u64* __restrict__ fP,
      u64* __restrict__ sT, u64* __restrict__ sP,
      int* __restrict__ prT, int* __restrict__ prP,
      int* __restrict__ rcT, int* __restrict__ rcP,
      float* __restrict__ runsumT, float* __restrict__ runsumP,
      int* __restrict__ parentT, int* __restrict__ parentP,
      double* __restrict__ part) {
    __shared__ int lab[SLOTS];
    __shared__ int rcL[2][SROWS];
    __shared__ double shd[NTHR_F / 64];

    const int tid = threadIdx.x;
    const int wid = tid >> 6, lane = tid & 63;
    const int img = blockIdx.x >> 5;            // STRIPS = 32
    const int strip = blockIdx.x & (STRIPS - 1);
    const int row0 = img * HH + strip * SROWS;  // chunk-local row base

    // ---------------- maskloss phase: 8 waves x 4 rows ----------------
    double lsum = 0.0;
    for (int j = 0; j < 4; ++j) {
        int rl = wid * 4 + j;
        int R = row0 + rl;
        long pixbase = (long)R * WW;
        long rbase = (long)R * RPR;
        const float4* p4 = (const float4*)(preds + gbase + pixbase);
        const float4* t4 = (const float4*)(targets + gbase + pixbase);
        float lossv[16];
        int maskT = 0, maskP = 0;
        float rowsum = 0.0f;
        #pragma unroll
        for (int jj = 0; jj < 4; ++jj) {
            float4 pv = p4[lane * 4 + jj];
            float4 tv = t4[lane * 4 + jj];
            float pp[4] = {pv.x, pv.y, pv.z, pv.w};
            float tt[4] = {tv.x, tv.y, tv.z, tv.w};
            #pragma unroll
            for (int q = 0; q < 4; ++q) {
                int k = jj * 4 + q;
                float p = pp[q], t = tt[q];
                float loss = fmaxf(p, 0.0f) - p * t + __logf(1.0f + __expf(-fabsf(p)));
                lossv[k] = loss;
                rowsum += loss;
                maskT |= ((int)(t > 0.0f)) << k;
                maskP |= ((int)(p > 0.5f)) << k;
            }
        }
        lsum += (double)rowsum;

        int mistT = maskT & ~maskP;
        int mistP = maskP & ~maskT;

        int pm = __shfl_up(maskT | (maskP << 16), 1, 64);
        int carryT = (lane == 0) ? 0 : ((pm >> 15) & 1);
        int carryP = (lane == 0) ? 0 : ((int)(((unsigned)pm) >> 31) & 1);
        int stT_ = maskT & ~((maskT << 1) | carryT) & 0xFFFF;
        int stP_ = maskP & ~((maskP << 1) | carryP) & 0xFFFF;

        int cntT = __popc(stT_), cntP = __popc(stP_);
        int incl2 = cntT | (cntP << 16);
        #pragma unroll
        for (int d = 1; d < 64; d <<= 1) {
            int u = __shfl_up(incl2, d, 64);
            if (lane >= d) incl2 += u;
        }
        int inclT = incl2 & 0xFFFF;
        int inclP = (int)(((unsigned)incl2) >> 16);
        int exT = inclT - cntT;
        int exP = inclP - cntP;

        phaseBody(lane, maskT, mistT, stT_, carryT, exT, inclT, lossv, rbase, runsumT);
        phaseBody(lane, maskP, mistP, stP_, carryP, exP, inclP, lossv, rbase, runsumP);
        if (lane == 63) {
            rcT[R] = inclT; rcP[R] = inclP;
            rcL[0][rl] = inclT; rcL[1][rl] = inclP;
        }

        int subid = lane & 15;
        int srcl = subid * 4;
        u64 fw = 0, sw = 0;
        #pragma unroll
        for (int jj = 0; jj < 4; ++jj) {
            int mT = __shfl(maskT, srcl + jj, 64);
            int mP = __shfl(maskP, srcl + jj, 64);
            int aT = __shfl(stT_, srcl + jj, 64);
            int aP = __shfl(stP_, srcl + jj, 64);
            u64 m = (u64)(unsigned)((lane < 16) ? mT : mP);
            u64 a = (u64)(unsigned)((lane < 16) ? aT : aP);
            fw |= (m & 0xFFFFULL) << (16 * jj);
            sw |= (a & 0xFFFFULL) << (16 * jj);
        }
        int eT = __shfl(exT, srcl, 64);
        int eP = __shfl(exP, srcl, 64);
        int wi = R * WPR + subid;
        if (lane < 16) { fT[wi] = fw; sT[wi] = sw; prT[wi] = eT; }
        else if (lane < 32) { fP[wi] = fw; sP[wi] = sw; prP[wi] = eP; }
    }
    lsum *= 0.5;
    #pragma unroll
    for (int off = 32; off > 0; off >>= 1) lsum += __shfl_down(lsum, off, 64);
    if (lane == 0) shd[wid] = lsum;
    __syncthreads();  // drains global writes; rcL/shd visible
    if (tid == 0) {
        double tot = 0.0;
        #pragma unroll
        for (int w = 0; w < NTHR_F / 64; ++w) tot += shd[w];
        part[blockIdx.x] += tot;
    }

    // ---------------- strip CCL: both phases, one 64KB lab ----------------
    const int gb = row0 * RPR;
    for (int ph = 0; ph < 2; ++ph) {
        const u64* f = ph ? fP : fT;
        const u64* s = ph ? sP : sT;
        const int* pr = ph ? prP : prT;
        const float* runsum = ph ? runsumP : runsumT;
        int* parent = ph ? parentP : parentT;

        // init used slots only
        for (int i = tid; i < SLOTS; i += NTHR_F)
            if ((i & (RPR - 1)) < rcL[ph][i >> 9]) lab[i] = i;
        __syncthreads();

        // intra-strip vertical unites, 2-way sub-word split
        for (int task = tid; task < (SROWS - 1) * WPR * 2; task += NTHR_F) {
            int j = task & 1, w = (task >> 1) & 15, r = task >> 5;
            int w0 = (row0 + r) * WPR + w, w1 = w0 + WPR;
            u64 o = f[w0] & f[w1];
            if (!o) continue;
            u64 s0 = s[w0], s1 = s[w1];
            int b0 = r * RPR + pr[w0], b1 = (r + 1) * RPR + pr[w1];
            u64 os = o & ~(o << 1);
            int k = 0;
            while (os) {
                int b = __builtin_ctzll(os);
                os &= os - 1;
                if ((k++ & 1) == j)
                    uniteL(lab, b0 + runIndexW(s0, b), b1 + runIndexW(s1, b));
            }
        }
        __syncthreads();

        // pass A: compress non-roots (tree static) + OR mistake flags onto roots.
        for (int i = tid; i < SLOTS; i += NTHR_F) {
            if ((i & (RPR - 1)) >= rcL[ph][i >> 9]) continue;
            int e = lab[i];
            int rt = e & IDXMASK;
            if (rt != i) {
                rt = findRootL(lab, i);
                parent[gb + i] = gb + rt;
            }
            if (__float_as_uint(runsum[gb + i]) >> 31) {
                if (!(((volatile int*)lab)[rt] & FLAGBIT)) atomicOr(&lab[rt], FLAGBIT);
            }
        }
        __syncthreads();

        // pass B: root entries carry their settled flag
        for (int i = tid; i < SLOTS; i += NTHR_F) {
            if ((i & (RPR - 1)) >= rcL[ph][i >> 9]) continue;
            int e = lab[i];
            if ((e & IDXMASK) == i) parent[gb + i] = (gb + i) | (e & FLAGBIT);
        }
        __syncthreads();  // lab reused next phase
    }
}

// Global flag-carrying unions across the 31 strip seams per image.
__global__ void k_bound(const u64* __restrict__ fT, const u64* __restrict__ fP,
                        const u64* __restrict__ sT, const u64* __restrict__ sP,
                        const int* __restrict__ prT, const int* __restrict__ prP,
                        int* __restrict__ parentT, int* __restrict__ parentP, int nb) {
    int tasks = nb * (STRIPS - 1) * WPR * 2;
    int stride = gridDim.x * blockDim.x;
    for (int id = blockIdx.x * blockDim.x + threadIdx.x; id < tasks; id += stride) {
        int ph = id & 1;
        int t = id >> 1;
        int w = t & 15; t >>= 4;
        int bnd = t % (STRIPS - 1);
        int img = t / (STRIPS - 1);
        int R = img * HH + bnd * SROWS + (SROWS - 1);  // last row of strip bnd
        const u64* f = ph ? fP : fT;
        const u64* s = ph ? sP : sT;
        const int* pr = ph ? prP : prT;
        int* parent = ph ? parentP : parentT;
        int w0 = R * WPR + w, w1 = w0 + WPR;
        u64 o = f[w0] & f[w1];
        if (!o) continue;
        u64 s0 = s[w0], s1 = s[w1];
        int b0 = R * RPR + pr[w0], b1 = (R + 1) * RPR + pr[w1];
        u64 os = o & ~(o << 1);
        while (os) {
            int b = __builtin_ctzll(os);
            os &= os - 1;
            uniteGF(parent, b0 + runIndexW(s0, b), b1 + runIndexW(s1, b));
        }
    }
}

// Per used run slot (x4 vectorized): root flag ? 0.25*|runsum| -> partials.
__global__ void k_accumrun(const int* __restrict__ rcT, const int* __restrict__ rcP,
                           int* __restrict__ parentT, int* __restrict__ parentP,
                           const float* __restrict__ runsumT, const float* __restrict__ runsumP,
                           double* __restrict__ part, int nslots) {
    int stride = gridDim.x * blockDim.x;
    double local = 0.0;
    int ngroups = nslots >> 2;  // 4 slots per group, always within one row
    for (int g = blockIdx.x * blockDim.x + threadIdx.x; g < ngroups; g += stride) {
        int base = g << 2;
        int row = base >> 9, k = base & (RPR - 1);
        int nT = rcT[row] - k, nP = rcP[row] - k;
        if (nT > 0) {
            int4 e4 = *(const int4*)&parentT[base];
            float4 r4 = *(const float4*)&runsumT[base];
            int ee[4] = {e4.x, e4.y, e4.z, e4.w};
            float rr[4] = {r4.x, r4.y, r4.z, r4.w};
            int n = nT < 4 ? nT : 4;
            for (int j = 0; j < n; ++j) {
                int e = ee[j];
                int r = e & IDXMASK;
                int fl;
                if (r == base + j) fl = e & FLAGBIT;
                else { r = findRootH(parentT, r); fl = parentT[r] & FLAGBIT; }
                if (fl) local += 0.25 * (double)fabsf(rr[j]);
            }
        }
        if (nP > 0) {
            int4 e4 = *(const int4*)&parentP[base];
            float4 r4 = *(const float4*)&runsumP[base];
            int ee[4] = {e4.x, e4.y, e4.z, e4.w};
            float rr[4] = {r4.x, r4.y, r4.z, r4.w};
            int n = nP < 4 ? nP : 4;
            for (int j = 0; j < n; ++j) {
                int e = ee[j];
                int r = e & IDXMASK;
                int fl;
                if (r == base + j) fl = e & FLAGBIT;
                else { r = findRootH(parentP, r); fl = parentP[r] & FLAGBIT; }
                if (fl) local += 0.25 * (double)fabsf(rr[j]);
            }
        }
    }
    #pragma unroll
    for (int off = 32; off > 0; off >>= 1) local += __shfl_down(local, off, 64);
    __shared__ double sh[NTHR / 64];
    int lane = threadIdx.x & 63, wid = threadIdx.x >> 6;
    if (lane == 0) sh[wid] = local;
    __syncthreads();
    if (threadIdx.x == 0) {
        double tot = 0.0;
        #pragma unroll
        for (int w = 0; w < NTHR / 64; ++w) tot += sh[w];
        part[blockIdx.x] += tot;
    }
}

__global__ void k_final(const double* __restrict__ part, float* __restrict__ out, double inv_n) {
    double v = 0.0;
    for (int i = threadIdx.x; i < NPART; i += blockDim.x) v += part[i];
    #pragma unroll
    for (int off = 32; off > 0; off >>= 1) v += __shfl_down(v, off, 64);
    __shared__ double sh[NTHR / 64];
    int lane = threadIdx.x & 63, wid = threadIdx.x >> 6;
    if (lane == 0) sh[wid] = v;
    __syncthreads();
    if (threadIdx.x == 0) {
        double tot = 0.0;
        #pragma unroll
        for (int w = 0; w < NTHR / 64; ++w) tot += sh[w];
        out[0] = (float)(tot * inv_n);
    }
}

extern "C" void kernel_launch(void* const* d_in, const int* in_sizes, int n_in,
                              void* d_out, int out_size, void* d_ws, size_t ws_size,
                              hipStream_t stream) {
    const float* preds = (const float*)d_in[0];
    const float* targets = (const float*)d_in[1];
    float* out = (float*)d_out;

    // ws: part | fT fP sT sP (u64) | prT prP rcT rcP parentT parentP (int)
    //    | runsumT runsumP (f32)           (chunked by image)
    double* part = (double*)d_ws;
    char* base = (char*)d_ws + NPART * sizeof(double);
    size_t avail = (ws_size > NPART * sizeof(double)) ? ws_size - NPART * sizeof(double) : 0;
    const size_t wpi = (size_t)HH * WPR;       // 16384 words per image
    const size_t runs_pi = (size_t)HH * RPR;   // 524288 run slots per image
    const size_t per_img = 4 * wpi * sizeof(u64) + 2 * wpi * sizeof(int)
                         + 2 * HH * sizeof(int) + 2 * runs_pi * sizeof(int)
                         + 2 * runs_pi * sizeof(float);  // ~9.1 MB
    int chunk = (int)(avail / per_img);
    if (chunk < 1) chunk = 1;
    if (chunk > NB_TOTAL) chunk = NB_TOTAL;

    u64* fT = (u64*)base;
    u64* fP = fT + (size_t)chunk * wpi;
    u64* sT = fP + (size_t)chunk * wpi;
    u64* sP = sT + (size_t)chunk * wpi;
    int* prT = (int*)(sP + (size_t)chunk * wpi);
    int* prP = prT + (size_t)chunk * wpi;
    int* rcT = prP + (size_t)chunk * wpi;
    int* rcP = rcT + (size_t)chunk * HH;
    int* parentT = rcP + (size_t)chunk * HH;
    int* parentP = parentT + (size_t)chunk * runs_pi;
    float* runsumT = (float*)(parentP + (size_t)chunk * runs_pi);
    float* runsumP = runsumT + (size_t)chunk * runs_pi;

    k_zero<<<NPART / NTHR, NTHR, 0, stream>>>(part);

    for (int b0 = 0; b0 < NB_TOTAL; b0 += chunk) {
        int nb = (b0 + chunk <= NB_TOTAL) ? chunk : (NB_TOTAL - b0);
        long gbase = (long)b0 * IMGPIX;
        int nslots = (int)(nb * runs_pi);

        k_mls<<<nb * STRIPS, NTHR_F, 0, stream>>>(preds, targets, gbase,
                                                  fT, fP, sT, sP, prT, prP, rcT, rcP,
                                                  runsumT, runsumP, parentT, parentP,
                                                  part);
        k_bound<<<512, NTHR, 0, stream>>>(fT, fP, sT, sP, prT, prP, parentT, parentP, nb);
        k_accumrun<<<NBLK, NTHR, 0, stream>>>(rcT, rcP, parentT, parentP,
                                              runsumT, runsumP, part, nslots);
    }

    double inv_n = 1.0 / ((double)NB_TOTAL * (double)IMGPIX);
    k_final<<<1, NTHR, 0, stream>>>(part, out, inv_n);
}

// Round 19
// 235.578 us; speedup vs baseline: 1.1843x; 1.1843x over previous
//
#include <hip/hip_runtime.h>
#include <math.h>

// SuperVoxel critical-component loss on MI355X.  (round-16 best + k_zero fold)
// mean( (0.5 + 0.25*neg + 0.25*pos) * bce_loss )
// Run-based two-level CCL with path-halving union-find and PER-RUN loss sums.
//  k_maskloss: 4 waves/block, one row per wave (16 px/lane, chunk-order float4
//              loads). Merged packed count scan (T|P<<16); segmented-scan
//              elision (ballot-guarded); mistake bit in runsum SIGN.
//              First chunk-iteration writes part[] with '=' (no k_zero).
//  k_strip:    32-row strips, intra-strip unions in 64KB LDS; compress pass A
//              ORs sign-bit mistake flags onto static roots.
//  k_bound:    global flag-carrying unions on 31 strip seams per image.
//  k_accumrun: per used run slot (x4 vectorized): root flag ? 0.25*|runsum|.

#define HH 1024
#define WW 1024
#define IMGPIX (HH * WW)
#define NB_TOTAL 16
#define FLAGBIT 0x40000000
#define IDXMASK 0x3FFFFFFF
#define NBLK 2048
#define NPART 2048
#define NTHR 256
#define WPR 16               // u64 mask words per row
#define RPR 512              // run slots per row (hard worst case)
#define SROWS 32             // rows per strip
#define STRIPS (HH / SROWS)  // 32 strips per image
#define SLOTS (SROWS * RPR)  // 16384 slots per strip (64KB LDS)
#define NTHR_S 1024

typedef unsigned long long u64;

// ---------- global union-find, path-halving, flag-aware ----------
__device__ __forceinline__ int findRootH(int* p, int i) {
    volatile int* vp = p;
    int r = i;
    int e = vp[r] & IDXMASK;
    while (e != r) {
        int e2 = vp[e] & IDXMASK;
        if (e2 != e) p[r] = e2;  // shortcut: only non-roots written (no flags there)
        r = e; e = e2;
    }
    return r;
}

__device__ __forceinline__ void flagProp(int* p, int x) {
    while (true) {
        int r = findRootH(p, x);
        int old = atomicOr(&p[r], FLAGBIT);
        if ((old & IDXMASK) == r) return;  // was still a root
        x = old & IDXMASK;
    }
}

__device__ __forceinline__ void uniteGF(int* p, int a, int b) {
    int ra = findRootH(p, a), rb = findRootH(p, b);
    while (ra != rb) {
        if (ra < rb) { int t = ra; ra = rb; rb = t; }  // hook larger under smaller
        int e = p[ra];
        if ((e & IDXMASK) != ra) { ra = findRootH(p, e & IDXMASK); continue; }
        int prev = atomicCAS(&p[ra], e, rb);
        if (prev == e) {
            if (e & FLAGBIT) flagProp(p, rb);
            return;
        }
        ra = findRootH(p, prev & IDXMASK);
        rb = findRootH(p, rb);
    }
}

// ---------- LDS union-find, path-halving ----------
__device__ __forceinline__ int findRootL(int* lab, int i) {
    volatile int* vl = lab;
    int r = i;
    int e = vl[r] & IDXMASK;
    while (e != r) {
        int e2 = vl[e] & IDXMASK;
        if (e2 != e) lab[r] = e2;
        r = e; e = e2;
    }
    return r;
}

__device__ __forceinline__ void uniteL(int* lab, int a, int b) {
    int ra = findRootL(lab, a), rb = findRootL(lab, b);
    while (ra != rb) {
        if (ra < rb) { int t = ra; ra = rb; rb = t; }
        int prev = atomicCAS(&lab[ra], ra, rb);
        if (prev == ra) return;
        ra = findRootL(lab, prev & IDXMASK);
        rb = findRootL(lab, rb);
    }
}

// index (within row) of the run containing bit b of this word; requires fg@b.
__device__ __forceinline__ int runIndexW(u64 starts, int b) {
    u64 below = (2ULL << b) - 1ULL;  // b=63 wraps to ~0ULL
    return (int)__popcll(starts & below) - 1;
}

__device__ __forceinline__ float packf(float mag, bool fl) {
    return __uint_as_float(__float_as_uint(mag) | (fl ? 0x80000000u : 0u));
}

// Per-phase body (after merged count scan): serial in-lane loop writes
// complete runs; trailing-run resolution is local unless some lane's mask is
// fully set (then the full 6-step segmented scan runs, ballot-guarded).
__device__ __forceinline__ void phaseBody(int lane, int mask, int mist, int starts,
                                          int carry, int excl, int incl,
                                          const float* lossv, long rbase,
                                          float* __restrict__ runsum) {
    float cur = 0.0f, headmag = 0.0f;
    bool curf = false, headf = false;
    bool begun = false, prevfg = (carry != 0), hasHead = false;
    int scount = 0;
    #pragma unroll
    for (int k = 0; k < 16; ++k) {
        bool fg = (mask >> k) & 1;
        bool mk = (mist >> k) & 1;
        if (fg) {
            if ((starts >> k) & 1) { cur = lossv[k]; curf = mk; begun = true; ++scount; }
            else { cur += lossv[k]; curf |= mk; }
        } else {
            if (prevfg) {
                if (begun) runsum[rbase + excl + scount - 1] = packf(cur, curf);
                else { hasHead = true; headmag = cur; headf = curf; }
            }
        }
        prevfg = fg;
    }
    // trailing-run sum: already complete unless a fully-set lane exists
    // (starts==0 && bit15 set  ==>  mask==0xFFFF).
    float sv = prevfg ? packf(cur, curf) : 0.0f;
    u64 fullb = __ballot(mask == 0xFFFF);
    if (fullb) {
        int fl = (starts != 0);
        #pragma unroll
        for (int d = 1; d < 64; d <<= 1) {
            float u = __shfl_up(sv, d, 64);
            int uf = __shfl_up(fl, d, 64);
            if (lane >= d) {
                if (!fl) {
                    unsigned sg = (__float_as_uint(sv) | __float_as_uint(u)) & 0x80000000u;
                    float mag = fabsf(sv) + fabsf(u);
                    sv = __uint_as_float(__float_as_uint(mag) | sg);
                }
                fl |= uf;
            }
        }
    }
    float svprev = __shfl_up(sv, 1, 64);
    if (hasHead) {
        unsigned sg = (__float_as_uint(svprev) & 0x80000000u) | (headf ? 0x80000000u : 0u);
        float mag = fabsf(svprev) + headmag;
        runsum[rbase + excl - 1] = __uint_as_float(__float_as_uint(mag) | sg);
    }
    if (lane == 63 && prevfg) runsum[rbase + incl - 1] = sv;  // keeps packed sign
}

// Wave-per-row, lane-chunk layout: lane l owns pixels [16l, 16l+16).
__global__ void k_maskloss(const float* __restrict__ preds, const float* __restrict__ targets,
                           long gbase, int nrows,
                           u64* __restrict__ fT, u64* __restrict__ fP,
                           u64* __restrict__ sT, u64* __restrict__ sP,
                           int* __restrict__ prT, int* __restrict__ prP,
                           int* __restrict__ rcT, int* __restrict__ rcP,
                           float* __restrict__ runsumT, float* __restrict__ runsumP,
                           double* __restrict__ part, int first) {
    __shared__ double sh[4];
    int wid = threadIdx.x >> 6, lane = threadIdx.x & 63;
    double lsum = 0.0;
    for (int R = blockIdx.x * 4 + wid; R < nrows; R += gridDim.x * 4) {
        long pixbase = (long)R * WW;
        long rbase = (long)R * RPR;
        const float4* p4 = (const float4*)(preds + gbase + pixbase);
        const float4* t4 = (const float4*)(targets + gbase + pixbase);
        float lossv[16];
        int maskT = 0, maskP = 0;
        float rowsum = 0.0f;
        #pragma unroll
        for (int j = 0; j < 4; ++j) {
            float4 pv = p4[lane * 4 + j];
            float4 tv = t4[lane * 4 + j];
            float pp[4] = {pv.x, pv.y, pv.z, pv.w};
            float tt[4] = {tv.x, tv.y, tv.z, tv.w};
            #pragma unroll
            for (int q = 0; q < 4; ++q) {
                int k = j * 4 + q;
                float p = pp[q], t = tt[q];
                float loss = fmaxf(p, 0.0f) - p * t + __logf(1.0f + __expf(-fabsf(p)));
                lossv[k] = loss;
                rowsum += loss;
                maskT |= ((int)(t > 0.0f)) << k;
                maskP |= ((int)(p > 0.5f)) << k;
            }
        }
        lsum += (double)rowsum;

        int mistT = maskT & ~maskP;
        int mistP = maskP & ~maskT;

        // carries for both phases via ONE packed shuffle
        int pm = __shfl_up(maskT | (maskP << 16), 1, 64);
        int carryT = (lane == 0) ? 0 : ((pm >> 15) & 1);
        int carryP = (lane == 0) ? 0 : ((int)(((unsigned)pm) >> 31) & 1);
        int stT_ = maskT & ~((maskT << 1) | carryT) & 0xFFFF;
        int stP_ = maskP & ~((maskP << 1) | carryP) & 0xFFFF;

        // MERGED count scan: cntT in low 16, cntP in high 16 (totals <= 512)
        int cntT = __popc(stT_), cntP = __popc(stP_);
        int incl2 = cntT | (cntP << 16);
        #pragma unroll
        for (int d = 1; d < 64; d <<= 1) {
            int u = __shfl_up(incl2, d, 64);
            if (lane >= d) incl2 += u;
        }
        int inclT = incl2 & 0xFFFF;
        int inclP = (int)(((unsigned)incl2) >> 16);
        int exT = inclT - cntT;
        int exP = inclP - cntP;

        phaseBody(lane, maskT, mistT, stT_, carryT, exT, inclT, lossv, rbase, runsumT);
        phaseBody(lane, maskP, mistP, stP_, carryP, exP, inclP, lossv, rbase, runsumP);
        if (lane == 63) { rcT[R] = inclT; rcP[R] = inclP; }

        // pack word-format outputs: lanes 0..15 -> T words, 16..31 -> P words
        int subid = lane & 15;
        int srcl = subid * 4;
        u64 fw = 0, sw = 0;
        #pragma unroll
        for (int j = 0; j < 4; ++j) {
            int mT = __shfl(maskT, srcl + j, 64);
            int mP = __shfl(maskP, srcl + j, 64);
            int aT = __shfl(stT_, srcl + j, 64);
            int aP = __shfl(stP_, srcl + j, 64);
            u64 m = (u64)(unsigned)((lane < 16) ? mT : mP);
            u64 a = (u64)(unsigned)((lane < 16) ? aT : aP);
            fw |= (m & 0xFFFFULL) << (16 * j);
            sw |= (a & 0xFFFFULL) << (16 * j);
        }
        int eT = __shfl(exT, srcl, 64);
        int eP = __shfl(exP, srcl, 64);
        int wi = R * WPR + subid;
        if (lane < 16) { fT[wi] = fw; sT[wi] = sw; prT[wi] = eT; }
        else if (lane < 32) { fP[wi] = fw; sP[wi] = sw; prP[wi] = eP; }
    }
    lsum *= 0.5;
    #pragma unroll
    for (int off = 32; off > 0; off >>= 1) lsum += __shfl_down(lsum, off, 64);
    if (lane == 0) sh[wid] = lsum;
    __syncthreads();
    if (threadIdx.x == 0) {
        double tot = sh[0] + sh[1] + sh[2] + sh[3];
        part[blockIdx.x] = first ? tot : (part[blockIdx.x] + tot);
    }
}

// One block per (image, strip, phase): intra-strip CCL in 64KB LDS.
// Mistake flags come from runsum sign; OR'd onto static roots in pass A.
__global__ __launch_bounds__(NTHR_S) void
k_strip(const u64* __restrict__ fT, const u64* __restrict__ fP,
        const u64* __restrict__ sT, const u64* __restrict__ sP,
        const int* __restrict__ prT, const int* __restrict__ prP,
        const int* __restrict__ rcT, const int* __restrict__ rcP,
        const float* __restrict__ runsumT, const float* __restrict__ runsumP,
        int* __restrict__ parentT, int* __restrict__ parentP) {
    __shared__ int lab[SLOTS];
    __shared__ int rcL[SROWS];
    int bid = blockIdx.x;
    int ph = bid & 1; bid >>= 1;
    int strip = bid & (STRIPS - 1);
    int img = bid >> 5;  // STRIPS = 32
    const u64* f = ph ? fP : fT;
    const u64* s = ph ? sP : sT;
    const int* pr = ph ? prP : prT;
    const int* rc = ph ? rcP : rcT;
    const float* runsum = ph ? runsumP : runsumT;
    int* parent = ph ? parentP : parentT;
    const int row0 = img * HH + strip * SROWS;

    if (threadIdx.x < SROWS) rcL[threadIdx.x] = rc[row0 + threadIdx.x];
    __syncthreads();

    // init used slots only
    for (int i = threadIdx.x; i < SLOTS; i += NTHR_S)
        if ((i & (RPR - 1)) < rcL[i >> 9]) lab[i] = i;
    __syncthreads();

    // intra-strip vertical unites, 2-way sub-word split
    for (int task = threadIdx.x; task < (SROWS - 1) * WPR * 2; task += NTHR_S) {
        int j = task & 1, w = (task >> 1) & 15, r = task >> 5;
        int w0 = (row0 + r) * WPR + w, w1 = w0 + WPR;
        u64 o = f[w0] & f[w1];
        if (!o) continue;
        u64 s0 = s[w0], s1 = s[w1];
        int b0 = r * RPR + pr[w0], b1 = (r + 1) * RPR + pr[w1];
        u64 os = o & ~(o << 1);
        int k = 0;
        while (os) {
            int b = __builtin_ctzll(os);
            os &= os - 1;
            if ((k++ & 1) == j)
                uniteL(lab, b0 + runIndexW(s0, b), b1 + runIndexW(s1, b));
        }
    }
    __syncthreads();

    // pass A: compress non-roots (tree static) + OR mistake flags onto roots.
    const int gb = row0 * RPR;
    for (int i = threadIdx.x; i < SLOTS; i += NTHR_S) {
        if ((i & (RPR - 1)) >= rcL[i >> 9]) continue;
        int e = lab[i];
        int rt = e & IDXMASK;
        if (rt != i) {
            rt = findRootL(lab, i);
            parent[gb + i] = gb + rt;
        }
        if (__float_as_uint(runsum[gb + i]) >> 31) {
            if (!(((volatile int*)lab)[rt] & FLAGBIT)) atomicOr(&lab[rt], FLAGBIT);
        }
    }
    __syncthreads();

    // pass B: root entries carry their settled flag
    for (int i = threadIdx.x; i < SLOTS; i += NTHR_S) {
        if ((i & (RPR - 1)) >= rcL[i >> 9]) continue;
        int e = lab[i];
        if ((e & IDXMASK) == i) parent[gb + i] = (gb + i) | (e & FLAGBIT);
    }
}

// Global flag-carrying unions across the 31 strip seams per image.
__global__ void k_bound(const u64* __restrict__ fT, const u64* __restrict__ fP,
                        const u64* __restrict__ sT, const u64* __restrict__ sP,
                        const int* __restrict__ prT, const int* __restrict__ prP,
                        int* __restrict__ parentT, int* __restrict__ parentP, int nb) {
    int tasks = nb * (STRIPS - 1) * WPR * 2;
    int stride = gridDim.x * blockDim.x;
    for (int id = blockIdx.x * blockDim.x + threadIdx.x; id < tasks; id += stride) {
        int ph = id & 1;
        int t = id >> 1;
        int w = t & 15; t >>= 4;
        int bnd = t % (STRIPS - 1);
        int img = t / (STRIPS - 1);
        int R = img * HH + bnd * SROWS + (SROWS - 1);  // last row of strip bnd
        const u64* f = ph ? fP : fT;
        const u64* s = ph ? sP : sT;
        const int* pr = ph ? prP : prT;
        int* parent = ph ? parentP : parentT;
        int w0 = R * WPR + w, w1 = w0 + WPR;
        u64 o = f[w0] & f[w1];
        if (!o) continue;
        u64 s0 = s[w0], s1 = s[w1];
        int b0 = R * RPR + pr[w0], b1 = (R + 1) * RPR + pr[w1];
        u64 os = o & ~(o << 1);
        while (os) {
            int b = __builtin_ctzll(os);
            os &= os - 1;
            uniteGF(parent, b0 + runIndexW(s0, b), b1 + runIndexW(s1, b));
        }
    }
}

// Per used run slot (x4 vectorized): root flag ? 0.25*|runsum| -> partials.
__global__ void k_accumrun(const int* __restrict__ rcT, const int* __restrict__ rcP,
                           int* __restrict__ parentT, int* __restrict__ parentP,
                           const float* __restrict__ runsumT, const float* __restrict__ runsumP,
                           double* __restrict__ part, int nslots) {
    int stride = gridDim.x * blockDim.x;
    double local = 0.0;
    int ngroups = nslots >> 2;  // 4 slots per group, always within one row
    for (int g = blockIdx.x * blockDim.x + threadIdx.x; g < ngroups; g += stride) {
        int base = g << 2;
        int row = base >> 9, k = base & (RPR - 1);
        int nT = rcT[row] - k, nP = rcP[row] - k;
        if (nT > 0) {
            int4 e4 = *(const int4*)&parentT[base];
            float4 r4 = *(const float4*)&runsumT[base];
            int ee[4] = {e4.x, e4.y, e4.z, e4.w};
            float rr[4] = {r4.x, r4.y, r4.z, r4.w};
            int n = nT < 4 ? nT : 4;
            for (int j = 0; j < n; ++j) {
                int e = ee[j];
                int r = e & IDXMASK;
                int fl;
                if (r == base + j) fl = e & FLAGBIT;
                else { r = findRootH(parentT, r); fl = parentT[r] & FLAGBIT; }
                if (fl) local += 0.25 * (double)fabsf(rr[j]);
            }
        }
        if (nP > 0) {
            int4 e4 = *(const int4*)&parentP[base];
            float4 r4 = *(const float4*)&runsumP[base];
            int ee[4] = {e4.x, e4.y, e4.z, e4.w};
            float rr[4] = {r4.x, r4.y, r4.z, r4.w};
            int n = nP < 4 ? nP : 4;
            for (int j = 0; j < n; ++j) {
                int e = ee[j];
                int r = e & IDXMASK;
                int fl;
                if (r == base + j) fl = e & FLAGBIT;
                else { r = findRootH(parentP, r); fl = parentP[r] & FLAGBIT; }
                if (fl) local += 0.25 * (double)fabsf(rr[j]);
            }
        }
    }
    #pragma unroll
    for (int off = 32; off > 0; off >>= 1) local += __shfl_down(local, off, 64);
    __shared__ double sh[NTHR / 64];
    int lane = threadIdx.x & 63, wid = threadIdx.x >> 6;
    if (lane == 0) sh[wid] = local;
    __syncthreads();
    if (threadIdx.x == 0) {
        double tot = 0.0;
        #pragma unroll
        for (int w = 0; w < NTHR / 64; ++w) tot += sh[w];
        part[blockIdx.x] += tot;
    }
}

__global__ void k_final(const double* __restrict__ part, float* __restrict__ out, double inv_n) {
    double v = 0.0;
    for (int i = threadIdx.x; i < NPART; i += blockDim.x) v += part[i];
    #pragma unroll
    for (int off = 32; off > 0; off >>= 1) v += __shfl_down(v, off, 64);
    __shared__ double sh[NTHR / 64];
    int lane = threadIdx.x & 63, wid = threadIdx.x >> 6;
    if (lane == 0) sh[wid] = v;
    __syncthreads();
    if (threadIdx.x == 0) {
        double tot = 0.0;
        #pragma unroll
        for (int w = 0; w < NTHR / 64; ++w) tot += sh[w];
        out[0] = (float)(tot * inv_n);
    }
}

extern "C" void kernel_launch(void* const* d_in, const int* in_sizes, int n_in,
                              void* d_out, int out_size, void* d_ws, size_t ws_size,
                              hipStream_t stream) {
    const float* preds = (const float*)d_in[0];
    const float* targets = (const float*)d_in[1];
    float* out = (float*)d_out;

    // ws: part | fT fP sT sP (u64) | prT prP rcT rcP parentT parentP (int)
    //    | runsumT runsumP (f32)           (chunked by image)
    double* part = (double*)d_ws;
    char* base = (char*)d_ws + NPART * sizeof(double);
    size_t avail = (ws_size > NPART * sizeof(double)) ? ws_size - NPART * sizeof(double) : 0;
    const size_t wpi = (size_t)HH * WPR;       // 16384 words per image
    const size_t runs_pi = (size_t)HH * RPR;   // 524288 run slots per image
    const size_t per_img = 4 * wpi * sizeof(u64) + 2 * wpi * sizeof(int)
                         + 2 * HH * sizeof(int) + 2 * runs_pi * sizeof(int)
                         + 2 * runs_pi * sizeof(float);  // ~9.1 MB
    int chunk = (int)(avail / per_img);
    if (chunk < 1) chunk = 1;
    if (chunk > NB_TOTAL) chunk = NB_TOTAL;

    u64* fT = (u64*)base;
    u64* fP = fT + (size_t)chunk * wpi;
    u64* sT = fP + (size_t)chunk * wpi;
    u64* sP = sT + (size_t)chunk * wpi;
    int* prT = (int*)(sP + (size_t)chunk * wpi);
    int* prP = prT + (size_t)chunk * wpi;
    int* rcT = prP + (size_t)chunk * wpi;
    int* rcP = rcT + (size_t)chunk * HH;
    int* parentT = rcP + (size_t)chunk * HH;
    int* parentP = parentT + (size_t)chunk * runs_pi;
    float* runsumT = (float*)(parentP + (size_t)chunk * runs_pi);
    float* runsumP = runsumT + (size_t)chunk * runs_pi;

    for (int b0 = 0; b0 < NB_TOTAL; b0 += chunk) {
        int nb = (b0 + chunk <= NB_TOTAL) ? chunk : (NB_TOTAL - b0);
        long gbase = (long)b0 * IMGPIX;
        int nrows = nb * HH;
        int nslots = (int)(nb * runs_pi);

        k_maskloss<<<NBLK, NTHR, 0, stream>>>(preds, targets, gbase, nrows,
                                              fT, fP, sT, sP, prT, prP, rcT, rcP,
                                              runsumT, runsumP, part, b0 == 0 ? 1 : 0);
        k_strip<<<nb * STRIPS * 2, NTHR_S, 0, stream>>>(fT, fP, sT, sP, prT, prP,
                                                        rcT, rcP, runsumT, runsumP,
                                                        parentT, parentP);
        k_bound<<<512, NTHR, 0, stream>>>(fT, fP, sT, sP, prT, prP, parentT, parentP, nb);
        k_accumrun<<<NBLK, NTHR, 0, stream>>>(rcT, rcP, parentT, parentP,
                                              runsumT, runsumP, part, nslots);
    }

    double inv_n = 1.0 / ((double)NB_TOTAL * (double)IMGPIX);
    k_final<<<1, NTHR, 0, stream>>>(part, out, inv_n);
}